// Round 1
// baseline (301.027 us; speedup 1.0000x reference)
//
#include <hip/hip_runtime.h>
#include <stdint.h>
#include <math.h>

// Problem constants: B=4, S=2048, D=1024
#define BATCH 4
#define SEQ   2048
#define DIM   1024
#define MROWS (BATCH * SEQ)   // 8192

// GEMM tile config (m93-style): 128x128 C-tile, BK=32, 256 threads (4 waves, 2x2),
// each wave computes 64x64 via 4x4 MFMA 16x16x32_bf16 subtiles.
#define BK 32
#define LSTR 40   // LDS row stride in bf16 elems (32 + 8 pad -> 80B, breaks 64B-stride conflicts)

typedef __attribute__((ext_vector_type(8))) short short8;
typedef __attribute__((ext_vector_type(4))) float floatx4;

__device__ __forceinline__ unsigned short f2bf(float f) {
    union { float f; unsigned u; } x; x.f = f;
    unsigned r = x.u + 0x7fffu + ((x.u >> 16) & 1u);  // RNE
    return (unsigned short)(r >> 16);
}

// ---------------- kernel 1: fp32 -> bf16 convert (x, Wq, Wk, Wv) ----------------
// x: 8388608 elems -> Xb ; Wq/Wk/Wv: 1048576 each -> Wb[0..3M) stacked (rows n: 0..3071)
__global__ void cvt_kernel(const float* __restrict__ x,
                           const float* __restrict__ wq,
                           const float* __restrict__ wk,
                           const float* __restrict__ wv,
                           unsigned short* __restrict__ xb,
                           unsigned short* __restrict__ wb) {
    int i4 = (blockIdx.x * 256 + threadIdx.x) * 4;   // total 11534336 elems, exact grid
    const float* src; unsigned short* dst; int off;
    if (i4 < 8388608)       { src = x;  dst = xb;            off = i4; }
    else if (i4 < 9437184)  { src = wq; dst = wb;            off = i4 - 8388608; }
    else if (i4 < 10485760) { src = wk; dst = wb + 1048576;  off = i4 - 9437184; }
    else                    { src = wv; dst = wb + 2097152;  off = i4 - 10485760; }
    float4 v = *(const float4*)(src + off);
    ushort4 o;
    o.x = f2bf(v.x); o.y = f2bf(v.y); o.z = f2bf(v.z); o.w = f2bf(v.w);
    *(ushort4*)(dst + off) = o;
}

// ---------------- shared GEMM pieces ----------------
// stage a 128x32 bf16 tile (row-major source, ld elems) into LDS with LSTR padding
__device__ __forceinline__ void stage_bf16(unsigned short* sh, const unsigned short* g,
                                           int ld, int tid) {
#pragma unroll
    for (int it = 0; it < 2; ++it) {
        int cid = it * 256 + tid;        // 512 chunks of 16B
        int row = cid >> 2, cc = cid & 3;
        uint4 v = *(const uint4*)(g + (size_t)row * ld + cc * 8);
        *(uint4*)(sh + row * LSTR + cc * 8) = v;
    }
}

// stage a 128x32 fp32 tile, converting to bf16 on the way into LDS
__device__ __forceinline__ void stage_f32(unsigned short* sh, const float* g,
                                          int ld, int tid) {
#pragma unroll
    for (int it = 0; it < 4; ++it) {
        int cid = it * 256 + tid;        // 1024 chunks of 16B (4 fp32)
        int row = cid >> 3, cc = cid & 7;
        float4 v = *(const float4*)(g + (size_t)row * ld + cc * 4);
        ushort4 o;
        o.x = f2bf(v.x); o.y = f2bf(v.y); o.z = f2bf(v.z); o.w = f2bf(v.w);
        *(ushort4*)(sh + row * LSTR + cc * 4) = o;
    }
}

// one BK=32 step: 16 MFMAs per wave.
// A-frag: lane holds A[m = lane&15][k = (lane>>4)*8 + j]; B^T-pattern B-frag identical.
__device__ __forceinline__ void mfma_step(const unsigned short* Ash, const unsigned short* Bsh,
                                          int lane, int wr, int wc, floatx4 acc[4][4]) {
    int lrow = lane & 15, lq = lane >> 4;
    short8 af[4], bf[4];
#pragma unroll
    for (int i = 0; i < 4; ++i) {
        af[i] = *(const short8*)(Ash + (wr * 64 + i * 16 + lrow) * LSTR + lq * 8);
        bf[i] = *(const short8*)(Bsh + (wc * 64 + i * 16 + lrow) * LSTR + lq * 8);
    }
#pragma unroll
    for (int i = 0; i < 4; ++i)
#pragma unroll
        for (int j = 0; j < 4; ++j)
            acc[i][j] = __builtin_amdgcn_mfma_f32_16x16x32_bf16(af[i], bf[j], acc[i][j], 0, 0, 0);
}

// ---------------- kernel 2: fused QKV projection GEMM ----------------
// C[m,n] = sum_k Xb[m,k] * Wb[n,k], m in [0,8192), n in [0,3072), K=1024
// n<1024 -> Q (row-major), n<2048 -> K (row-major), else V stored TRANSPOSED: Vt[b][d][s]
__global__ __launch_bounds__(256) void qkv_gemm(const unsigned short* __restrict__ Xb,
                                                const unsigned short* __restrict__ Wb,
                                                unsigned short* __restrict__ Qb,
                                                unsigned short* __restrict__ Kb,
                                                unsigned short* __restrict__ Vt) {
    __shared__ unsigned short Ash[128 * LSTR];
    __shared__ unsigned short Bsh[128 * LSTR];
    int tid = threadIdx.x;
    int bm = blockIdx.x, bn = blockIdx.y;
    int lane = tid & 63, w = tid >> 6, wr = w >> 1, wc = w & 1;
    floatx4 acc[4][4];
#pragma unroll
    for (int i = 0; i < 4; ++i)
#pragma unroll
        for (int j = 0; j < 4; ++j) acc[i][j] = (floatx4){0.f, 0.f, 0.f, 0.f};

    const unsigned short* Ag = Xb + (size_t)bm * 128 * 1024;
    const unsigned short* Bg = Wb + (size_t)bn * 128 * 1024;
    for (int k0 = 0; k0 < 1024; k0 += BK) {
        __syncthreads();
        stage_bf16(Ash, Ag + k0, 1024, tid);
        stage_bf16(Bsh, Bg + k0, 1024, tid);
        __syncthreads();
        mfma_step(Ash, Bsh, lane, wr, wc, acc);
    }

    int lrow = lane & 15, lq = lane >> 4;
#pragma unroll
    for (int i = 0; i < 4; ++i) {
        int mbase = bm * 128 + wr * 64 + i * 16 + lq * 4;  // global row m (4 consecutive)
#pragma unroll
        for (int j = 0; j < 4; ++j) {
            int n = bn * 128 + wc * 64 + j * 16 + lrow;
            int which = n >> 10, nn = n & 1023;
            if (which == 0) {
#pragma unroll
                for (int r = 0; r < 4; ++r)
                    Qb[(size_t)(mbase + r) * 1024 + nn] = f2bf(acc[i][j][r]);
            } else if (which == 1) {
#pragma unroll
                for (int r = 0; r < 4; ++r)
                    Kb[(size_t)(mbase + r) * 1024 + nn] = f2bf(acc[i][j][r]);
            } else {
                int b = mbase >> 11, s = mbase & 2047;
                ushort4 o;
                o.x = f2bf(acc[i][j][0]); o.y = f2bf(acc[i][j][1]);
                o.z = f2bf(acc[i][j][2]); o.w = f2bf(acc[i][j][3]);
                *(ushort4*)(Vt + ((size_t)b * 1024 + nn) * 2048 + s) = o;
            }
        }
    }
}

// ---------------- kernel 3: scores = (Q K^T)/32, causal+pad mask, fp32, lower tiles only ----
__global__ __launch_bounds__(256) void scores_gemm(const unsigned short* __restrict__ Qb,
                                                   const unsigned short* __restrict__ Kb,
                                                   const int* __restrict__ mask,
                                                   float* __restrict__ Sf) {
    int ti = blockIdx.x, tj = blockIdx.y, b = blockIdx.z;
    if (tj > ti) return;  // strictly-upper tiles never written, never read
    __shared__ unsigned short Ash[128 * LSTR];
    __shared__ unsigned short Bsh[128 * LSTR];
    int tid = threadIdx.x;
    int lane = tid & 63, w = tid >> 6, wr = w >> 1, wc = w & 1;
    floatx4 acc[4][4];
#pragma unroll
    for (int i = 0; i < 4; ++i)
#pragma unroll
        for (int j = 0; j < 4; ++j) acc[i][j] = (floatx4){0.f, 0.f, 0.f, 0.f};

    const unsigned short* Ag = Qb + ((size_t)b * 2048 + ti * 128) * 1024;
    const unsigned short* Bg = Kb + ((size_t)b * 2048 + tj * 128) * 1024;
    for (int k0 = 0; k0 < 1024; k0 += BK) {
        __syncthreads();
        stage_bf16(Ash, Ag + k0, 1024, tid);
        stage_bf16(Bsh, Bg + k0, 1024, tid);
        __syncthreads();
        mfma_step(Ash, Bsh, lane, wr, wc, acc);
    }

    float* Srow = Sf + (size_t)b * 2048 * 2048;
    int lrow = lane & 15, lq = lane >> 4;
#pragma unroll
    for (int i = 0; i < 4; ++i) {
        int qrow = ti * 128 + wr * 64 + i * 16 + lq * 4;
#pragma unroll
        for (int j = 0; j < 4; ++j) {
            int n = tj * 128 + wc * 64 + j * 16 + lrow;  // key col
            int mk = mask[b * 2048 + n];
#pragma unroll
            for (int r = 0; r < 4; ++r) {
                int q = qrow + r;
                float v = acc[i][j][r] * 0.03125f;  // 1/sqrt(1024)
                if (n > q || mk == 0) v = -INFINITY;
                Srow[(size_t)q * 2048 + n] = v;
            }
        }
    }
}

// ---------------- kernel 4: row softmax, in-place fp32, one block per (b,q) row -------------
__global__ __launch_bounds__(256) void softmax_k(float* __restrict__ Sf) {
    int bid = blockIdx.x;            // b*2048 + q
    int q = bid & 2047;
    int t = threadIdx.x;
    float* row = Sf + (size_t)bid * 2048;
    int Lw = ((q >> 7) + 1) << 7;    // written extent (tile-aligned), multiple of 128
    int base = t * 8;
    bool act = base < Lw;
    float v[8];
    if (act) {
        float4 a = *(const float4*)(row + base);
        float4 c = *(const float4*)(row + base + 4);
        v[0] = a.x; v[1] = a.y; v[2] = a.z; v[3] = a.w;
        v[4] = c.x; v[5] = c.y; v[6] = c.z; v[7] = c.w;
    } else {
#pragma unroll
        for (int r = 0; r < 8; ++r) v[r] = -INFINITY;
    }
    float m = -INFINITY;
#pragma unroll
    for (int r = 0; r < 8; ++r) m = fmaxf(m, v[r]);
#pragma unroll
    for (int o = 32; o >= 1; o >>= 1) m = fmaxf(m, __shfl_xor(m, o));
    __shared__ float red[4];
    if ((t & 63) == 0) red[t >> 6] = m;
    __syncthreads();
    m = fmaxf(fmaxf(red[0], red[1]), fmaxf(red[2], red[3]));

    float s = 0.f;
    if (act) {
#pragma unroll
        for (int r = 0; r < 8; ++r) { v[r] = __expf(v[r] - m); s += v[r]; }
    }
#pragma unroll
    for (int o = 32; o >= 1; o >>= 1) s += __shfl_xor(s, o);
    __syncthreads();                  // red reuse
    if ((t & 63) == 0) red[t >> 6] = s;
    __syncthreads();
    s = red[0] + red[1] + red[2] + red[3];
    float inv = 1.f / s;
    if (act) {
        float4 a, c;
        a.x = v[0] * inv; a.y = v[1] * inv; a.z = v[2] * inv; a.w = v[3] * inv;
        c.x = v[4] * inv; c.y = v[5] * inv; c.z = v[6] * inv; c.w = v[7] * inv;
        *(float4*)(row + base) = a;
        *(float4*)(row + base + 4) = c;
    }
}

// ---------------- kernel 5: O = P V  (P fp32 -> bf16 in staging; Vt is [b][d][s]) ----------
__global__ __launch_bounds__(256) void pv_gemm(const float* __restrict__ Pf,
                                               const unsigned short* __restrict__ Vt,
                                               float* __restrict__ out) {
    int ti = blockIdx.x;   // q tile (16)
    int dj = blockIdx.y;   // d tile (8)
    int b  = blockIdx.z;
    __shared__ unsigned short Ash[128 * LSTR];
    __shared__ unsigned short Bsh[128 * LSTR];
    int tid = threadIdx.x;
    int lane = tid & 63, w = tid >> 6, wr = w >> 1, wc = w & 1;
    floatx4 acc[4][4];
#pragma unroll
    for (int i = 0; i < 4; ++i)
#pragma unroll
        for (int j = 0; j < 4; ++j) acc[i][j] = (floatx4){0.f, 0.f, 0.f, 0.f};

    const float* Ag = Pf + ((size_t)b * 2048 + ti * 128) * 2048;
    const unsigned short* Bg = Vt + ((size_t)b * 1024 + dj * 128) * 2048;
    int kend = (ti + 1) * 128;   // causal extent (P beyond diag tile is exact 0 within it)
    for (int k0 = 0; k0 < kend; k0 += BK) {
        __syncthreads();
        stage_f32(Ash, Ag + k0, 2048, tid);
        stage_bf16(Bsh, Bg + k0, 2048, tid);
        __syncthreads();
        mfma_step(Ash, Bsh, lane, wr, wc, acc);
    }

    int lrow = lane & 15, lq = lane >> 4;
#pragma unroll
    for (int i = 0; i < 4; ++i) {
        int qrow = ti * 128 + wr * 64 + i * 16 + lq * 4;
#pragma unroll
        for (int j = 0; j < 4; ++j) {
            int d = dj * 128 + wc * 64 + j * 16 + lrow;
#pragma unroll
            for (int r = 0; r < 4; ++r)
                out[((size_t)b * 2048 + qrow + r) * 1024 + d] = acc[i][j][r];
        }
    }
}

// ---------------- launch ----------------
extern "C" void kernel_launch(void* const* d_in, const int* in_sizes, int n_in,
                              void* d_out, int out_size, void* d_ws, size_t ws_size,
                              hipStream_t stream) {
    const float* x    = (const float*)d_in[0];
    const int*   mask = (const int*)d_in[1];
    const float* wq   = (const float*)d_in[2];
    const float* wk   = (const float*)d_in[3];
    const float* wv   = (const float*)d_in[4];
    float* out = (float*)d_out;
    char* ws = (char*)d_ws;

    // workspace layout (bytes):
    unsigned short* Xb = (unsigned short*)(ws + 0);           // 16 MiB  bf16 x
    unsigned short* Wb = (unsigned short*)(ws + 16777216);    //  6 MiB  bf16 Wq|Wk|Wv rows
    unsigned short* Qb = (unsigned short*)(ws + 23068672);    // 16 MiB  bf16 Q [8192,1024]
    unsigned short* Kb = (unsigned short*)(ws + 39845888);    // 16 MiB  bf16 K [8192,1024]
    unsigned short* Vt = (unsigned short*)(ws + 56623104);    // 16 MiB  bf16 V^T [4,1024,2048]
    float*          Sf = (float*)(ws + 73400320);             // 64 MiB  fp32 scores/P [4,2048,2048]
    (void)ws_size; (void)in_sizes; (void)n_in; (void)out_size;

    cvt_kernel<<<11264, 256, 0, stream>>>(x, wq, wk, wv, Xb, Wb);
    qkv_gemm<<<dim3(64, 24), 256, 0, stream>>>(Xb, Wb, Qb, Kb, Vt);
    scores_gemm<<<dim3(16, 16, 4), 256, 0, stream>>>(Qb, Kb, mask, Sf);
    softmax_k<<<8192, 256, 0, stream>>>(Sf);
    pv_gemm<<<dim3(16, 8, 4), 256, 0, stream>>>(Sf, Vt, out);
}

// Round 2
// 251.144 us; speedup vs baseline: 1.1986x; 1.1986x over previous
//
#include <hip/hip_runtime.h>
#include <stdint.h>
#include <math.h>

// Problem constants: B=4, S=2048, D=1024
#define BATCH 4
#define SEQ   2048
#define DIM   1024

// GEMM tile config (m97-style): 128x128 C-tile, BK=32, 256 threads (4 waves, 2x2),
// each wave computes 64x64 via 4x4 MFMA 16x16x32_bf16 subtiles.
// LDS is UNPADDED (LSTR=32) because global_load_lds writes base + lane*16.
#define BK 32
#define LSTR 32

typedef __attribute__((ext_vector_type(8))) short short8;
typedef __attribute__((ext_vector_type(4))) float floatx4;

typedef __attribute__((address_space(3))) unsigned int lds_u32;
typedef const __attribute__((address_space(1))) unsigned int glb_u32;

__device__ __forceinline__ unsigned short f2bf(float f) {
    union { float f; unsigned u; } x; x.f = f;
    unsigned r = x.u + 0x7fffu + ((x.u >> 16) & 1u);  // RNE
    return (unsigned short)(r >> 16);
}

// ---------------- kernel 1: fp32 -> bf16 convert (x, Wq, Wk, Wv) ----------------
__global__ void cvt_kernel(const float* __restrict__ x,
                           const float* __restrict__ wq,
                           const float* __restrict__ wk,
                           const float* __restrict__ wv,
                           unsigned short* __restrict__ xb,
                           unsigned short* __restrict__ wb) {
    int i4 = (blockIdx.x * 256 + threadIdx.x) * 4;   // total 11534336 elems, exact grid
    const float* src; unsigned short* dst; int off;
    if (i4 < 8388608)       { src = x;  dst = xb;            off = i4; }
    else if (i4 < 9437184)  { src = wq; dst = wb;            off = i4 - 8388608; }
    else if (i4 < 10485760) { src = wk; dst = wb + 1048576;  off = i4 - 9437184; }
    else                    { src = wv; dst = wb + 2097152;  off = i4 - 10485760; }
    float4 v = *(const float4*)(src + off);
    ushort4 o;
    o.x = f2bf(v.x); o.y = f2bf(v.y); o.z = f2bf(v.z); o.w = f2bf(v.w);
    *(ushort4*)(dst + off) = o;
}

// ---------------- shared GEMM pieces ----------------
// async-stage a 128x32 bf16 tile (row-major, ld elems) into unpadded LDS.
// chunk c (of 512 x 16B): row=c>>2, col16B=c&3; LDS offset = c*16 bytes, which is
// per-wave base + lane*16 -- exactly the HW's global_load_lds addressing.
__device__ __forceinline__ void stage_async(unsigned short* sh, const unsigned short* g,
                                            int ld, int tid) {
#pragma unroll
    for (int it = 0; it < 2; ++it) {
        int c = it * 256 + tid;
        int row = c >> 2, cc = c & 3;
        __builtin_amdgcn_global_load_lds(
            (glb_u32*)(g + (size_t)row * ld + cc * 8),
            (lds_u32*)(sh + c * 8), 16, 0, 0);
    }
}

// one BK=32 step: 16 MFMAs per wave.
// A-frag: lane holds A[m = lane&15][k = (lane>>4)*8 + j]; B^T-pattern B-frag identical.
__device__ __forceinline__ void mfma_step(const unsigned short* Ash, const unsigned short* Bsh,
                                          int lane, int wr, int wc, floatx4 acc[4][4]) {
    int lrow = lane & 15, lq = lane >> 4;
    short8 af[4], bf[4];
#pragma unroll
    for (int i = 0; i < 4; ++i) {
        af[i] = *(const short8*)(Ash + (wr * 64 + i * 16 + lrow) * LSTR + lq * 8);
        bf[i] = *(const short8*)(Bsh + (wc * 64 + i * 16 + lrow) * LSTR + lq * 8);
    }
#pragma unroll
    for (int i = 0; i < 4; ++i)
#pragma unroll
        for (int j = 0; j < 4; ++j)
            acc[i][j] = __builtin_amdgcn_mfma_f32_16x16x32_bf16(af[i], bf[j], acc[i][j], 0, 0, 0);
}

// ---------------- kernel 2: fused QKV projection GEMM ----------------
// C[m,n] = sum_k Xb[m,k] * Wb[n,k], m in [0,8192), n in [0,3072), K=1024
// n<1024 -> Q (row-major), n<2048 -> K (row-major), else V stored TRANSPOSED: Vt[b][d][s]
__global__ __launch_bounds__(256) void qkv_gemm(const unsigned short* __restrict__ Xb,
                                                const unsigned short* __restrict__ Wb,
                                                unsigned short* __restrict__ Qb,
                                                unsigned short* __restrict__ Kb,
                                                unsigned short* __restrict__ Vt) {
    __shared__ unsigned short Ash[128 * LSTR];
    __shared__ unsigned short Bsh[128 * LSTR];
    int tid = threadIdx.x;
    int bm = blockIdx.x, bn = blockIdx.y;
    int lane = tid & 63, w = tid >> 6, wr = w >> 1, wc = w & 1;
    floatx4 acc[4][4];
#pragma unroll
    for (int i = 0; i < 4; ++i)
#pragma unroll
        for (int j = 0; j < 4; ++j) acc[i][j] = (floatx4){0.f, 0.f, 0.f, 0.f};

    const unsigned short* Ag = Xb + (size_t)bm * 128 * 1024;
    const unsigned short* Bg = Wb + (size_t)bn * 128 * 1024;
    for (int k0 = 0; k0 < 1024; k0 += BK) {
        __syncthreads();
        stage_async(Ash, Ag + k0, 1024, tid);
        stage_async(Bsh, Bg + k0, 1024, tid);
        __syncthreads();
        mfma_step(Ash, Bsh, lane, wr, wc, acc);
    }

    int lrow = lane & 15, lq = lane >> 4;
#pragma unroll
    for (int i = 0; i < 4; ++i) {
        int mbase = bm * 128 + wr * 64 + i * 16 + lq * 4;  // global row m (4 consecutive)
#pragma unroll
        for (int j = 0; j < 4; ++j) {
            int n = bn * 128 + wc * 64 + j * 16 + lrow;
            int which = n >> 10, nn = n & 1023;
            if (which == 0) {
#pragma unroll
                for (int r = 0; r < 4; ++r)
                    Qb[(size_t)(mbase + r) * 1024 + nn] = f2bf(acc[i][j][r]);
            } else if (which == 1) {
#pragma unroll
                for (int r = 0; r < 4; ++r)
                    Kb[(size_t)(mbase + r) * 1024 + nn] = f2bf(acc[i][j][r]);
            } else {
                int b = mbase >> 11, s = mbase & 2047;
                ushort4 o;
                o.x = f2bf(acc[i][j][0]); o.y = f2bf(acc[i][j][1]);
                o.z = f2bf(acc[i][j][2]); o.w = f2bf(acc[i][j][3]);
                *(ushort4*)(Vt + ((size_t)b * 1024 + nn) * 2048 + s) = o;
            }
        }
    }
}

// ---------------- kernel 3: scores = (Q K^T)/32, causal+pad mask, fp32, lower tiles only ----
// grid: (136 lower-tri tile pairs, 4 batches)
__global__ __launch_bounds__(256) void scores_gemm(const unsigned short* __restrict__ Qb,
                                                   const unsigned short* __restrict__ Kb,
                                                   const int* __restrict__ mask,
                                                   float* __restrict__ Sf) {
    int u = blockIdx.x, b = blockIdx.y;
    // triangular decode: u -> (ti, tj), tj <= ti
    int ti = (int)((sqrtf(8.0f * (float)u + 1.0f) - 1.0f) * 0.5f);
    while ((ti + 1) * (ti + 2) / 2 <= u) ti++;
    while (ti * (ti + 1) / 2 > u) ti--;
    int tj = u - ti * (ti + 1) / 2;

    __shared__ unsigned short Ash[128 * LSTR];
    __shared__ unsigned short Bsh[128 * LSTR];
    int tid = threadIdx.x;
    int lane = tid & 63, w = tid >> 6, wr = w >> 1, wc = w & 1;
    floatx4 acc[4][4];
#pragma unroll
    for (int i = 0; i < 4; ++i)
#pragma unroll
        for (int j = 0; j < 4; ++j) acc[i][j] = (floatx4){0.f, 0.f, 0.f, 0.f};

    const unsigned short* Ag = Qb + ((size_t)b * 2048 + ti * 128) * 1024;
    const unsigned short* Bg = Kb + ((size_t)b * 2048 + tj * 128) * 1024;
    for (int k0 = 0; k0 < 1024; k0 += BK) {
        __syncthreads();
        stage_async(Ash, Ag + k0, 1024, tid);
        stage_async(Bsh, Bg + k0, 1024, tid);
        __syncthreads();
        mfma_step(Ash, Bsh, lane, wr, wc, acc);
    }

    float* Srow = Sf + (size_t)b * 2048 * 2048;
    int lrow = lane & 15, lq = lane >> 4;
#pragma unroll
    for (int i = 0; i < 4; ++i) {
        int qrow = ti * 128 + wr * 64 + i * 16 + lq * 4;
#pragma unroll
        for (int j = 0; j < 4; ++j) {
            int n = tj * 128 + wc * 64 + j * 16 + lrow;  // key col
            int mk = mask[b * 2048 + n];
#pragma unroll
            for (int r = 0; r < 4; ++r) {
                int q = qrow + r;
                float v = acc[i][j][r] * 0.03125f;  // 1/sqrt(1024)
                if (n > q || mk == 0) v = -INFINITY;
                Srow[(size_t)q * 2048 + n] = v;
            }
        }
    }
}

// ---------------- kernel 4: row softmax, fp32 in -> bf16 P IN PLACE -------------
// Reads fp32 row of Sf, writes bf16 P into the first half of the same row
// (row stride stays 8192 B; bf16 view ld = 4096 ushorts). Safe: all loads complete
// before the reduction __syncthreads, all stores after.
__global__ __launch_bounds__(256) void softmax_k(float* __restrict__ Sf) {
    int bid = blockIdx.x;            // b*2048 + q
    int q = bid & 2047;
    int t = threadIdx.x;
    float* row = Sf + (size_t)bid * 2048;
    unsigned short* prow = (unsigned short*)row;   // bf16 view of same row
    int Lw = ((q >> 7) + 1) << 7;    // written extent (tile-aligned), multiple of 128
    int base = t * 8;
    bool act = base < Lw;
    float v[8];
    if (act) {
        float4 a = *(const float4*)(row + base);
        float4 c = *(const float4*)(row + base + 4);
        v[0] = a.x; v[1] = a.y; v[2] = a.z; v[3] = a.w;
        v[4] = c.x; v[5] = c.y; v[6] = c.z; v[7] = c.w;
    } else {
#pragma unroll
        for (int r = 0; r < 8; ++r) v[r] = -INFINITY;
    }
    float m = -INFINITY;
#pragma unroll
    for (int r = 0; r < 8; ++r) m = fmaxf(m, v[r]);
#pragma unroll
    for (int o = 32; o >= 1; o >>= 1) m = fmaxf(m, __shfl_xor(m, o));
    __shared__ float red[4];
    if ((t & 63) == 0) red[t >> 6] = m;
    __syncthreads();
    m = fmaxf(fmaxf(red[0], red[1]), fmaxf(red[2], red[3]));

    float s = 0.f;
    if (act) {
#pragma unroll
        for (int r = 0; r < 8; ++r) { v[r] = __expf(v[r] - m); s += v[r]; }
    }
#pragma unroll
    for (int o = 32; o >= 1; o >>= 1) s += __shfl_xor(s, o);
    __syncthreads();                  // red reuse
    if ((t & 63) == 0) red[t >> 6] = s;
    __syncthreads();
    s = red[0] + red[1] + red[2] + red[3];
    float inv = 1.f / s;
    if (act) {
        union { ushort4 u4[2]; unsigned short u[8]; } o;
#pragma unroll
        for (int r = 0; r < 8; ++r) o.u[r] = f2bf(v[r] * inv);
        *(ushort4*)(prow + base) = o.u4[0];
        *(ushort4*)(prow + base + 4) = o.u4[1];
    }
}

// ---------------- kernel 5: O = P V  (P bf16 in-place in Sf, ld 4096; Vt is [b][d][s]) -----
// 1D grid, ti decoded DESCENDING so the 2048-K blocks dispatch first (causal imbalance).
__global__ __launch_bounds__(256) void pv_gemm(const unsigned short* __restrict__ Pb,
                                               const unsigned short* __restrict__ Vt,
                                               float* __restrict__ out) {
    int bid = blockIdx.x;            // 512 blocks
    int ti = 15 - (bid >> 5);        // q tile, longest first
    int dj = (bid >> 2) & 7;         // d tile
    int b  = bid & 3;
    __shared__ unsigned short Ash[128 * LSTR];
    __shared__ unsigned short Bsh[128 * LSTR];
    int tid = threadIdx.x;
    int lane = tid & 63, w = tid >> 6, wr = w >> 1, wc = w & 1;
    floatx4 acc[4][4];
#pragma unroll
    for (int i = 0; i < 4; ++i)
#pragma unroll
        for (int j = 0; j < 4; ++j) acc[i][j] = (floatx4){0.f, 0.f, 0.f, 0.f};

    const unsigned short* Ag = Pb + ((size_t)b * 2048 + ti * 128) * 4096;  // bf16 view ld=4096
    const unsigned short* Bg = Vt + ((size_t)b * 1024 + dj * 128) * 2048;
    int kend = (ti + 1) * 128;   // causal extent (P beyond this is never needed)
    for (int k0 = 0; k0 < kend; k0 += BK) {
        __syncthreads();
        stage_async(Ash, Ag + k0, 4096, tid);
        stage_async(Bsh, Bg + k0, 2048, tid);
        __syncthreads();
        mfma_step(Ash, Bsh, lane, wr, wc, acc);
    }

    int lrow = lane & 15, lq = lane >> 4;
#pragma unroll
    for (int i = 0; i < 4; ++i) {
        int qrow = ti * 128 + wr * 64 + i * 16 + lq * 4;
#pragma unroll
        for (int j = 0; j < 4; ++j) {
            int d = dj * 128 + wc * 64 + j * 16 + lrow;
#pragma unroll
            for (int r = 0; r < 4; ++r)
                out[((size_t)b * 2048 + qrow + r) * 1024 + d] = acc[i][j][r];
        }
    }
}

// ---------------- launch ----------------
extern "C" void kernel_launch(void* const* d_in, const int* in_sizes, int n_in,
                              void* d_out, int out_size, void* d_ws, size_t ws_size,
                              hipStream_t stream) {
    const float* x    = (const float*)d_in[0];
    const int*   mask = (const int*)d_in[1];
    const float* wq   = (const float*)d_in[2];
    const float* wk   = (const float*)d_in[3];
    const float* wv   = (const float*)d_in[4];
    float* out = (float*)d_out;
    char* ws = (char*)d_ws;

    // workspace layout (bytes):
    unsigned short* Xb = (unsigned short*)(ws + 0);           // 16 MiB  bf16 x
    unsigned short* Wb = (unsigned short*)(ws + 16777216);    //  6 MiB  bf16 Wq|Wk|Wv rows
    unsigned short* Qb = (unsigned short*)(ws + 23068672);    // 16 MiB  bf16 Q [8192,1024]
    unsigned short* Kb = (unsigned short*)(ws + 39845888);    // 16 MiB  bf16 K [8192,1024]
    unsigned short* Vt = (unsigned short*)(ws + 56623104);    // 16 MiB  bf16 V^T [4,1024,2048]
    float*          Sf = (float*)(ws + 73400320);             // 64 MiB  fp32 scores -> bf16 P
    (void)ws_size; (void)in_sizes; (void)n_in; (void)out_size;

    cvt_kernel<<<11264, 256, 0, stream>>>(x, wq, wk, wv, Xb, Wb);
    qkv_gemm<<<dim3(64, 24), 256, 0, stream>>>(Xb, Wb, Qb, Kb, Vt);
    scores_gemm<<<dim3(136, 4), 256, 0, stream>>>(Qb, Kb, mask, Sf);
    softmax_k<<<8192, 256, 0, stream>>>(Sf);
    pv_gemm<<<512, 256, 0, stream>>>((const unsigned short*)Sf, Vt, out);
}